// Round 8
// baseline (134.749 us; speedup 1.0000x reference)
//
#include <hip/hip_runtime.h>
#include <math.h>

// Attn: out = softmax(tanh(Q) @ H^T) @ H ; B=8, Q=2048, K=2048, Hdim=128, fp32 in/out.
// R10 = R9 resubmitted verbatim (round 7 was an infra failure, no measurement).
// R9: occupancy + softmax-VALU round. Main: 4 waves x 32 q (128 q/block), K double-
//     buffered / V single-buffered (48KB LDS -> 3 blocks/CU), splits=6 (grid 768 =
//     3 resident blocks/CU, 12 waves/CU) for cross-block phase overlap of the
//     VALU-bound softmax. 3 barriers/kt, counted vmcnt (WAITVM4 steady state).
//     Softmax micro-cuts: v_max3 tree for row-max, fdot2 on packed f16 P for row-sum.

typedef _Float16 half8  __attribute__((ext_vector_type(8)));
typedef _Float16 half4  __attribute__((ext_vector_type(4)));
typedef __fp16   fp16x2 __attribute__((ext_vector_type(2)));   // cvt_pkrtz/fdot2 native type
typedef float    f32x4  __attribute__((ext_vector_type(4)));
typedef float    f32x16 __attribute__((ext_vector_type(16)));

#define QQ 2048
#define KK 2048
#define HH 128
#define QBM 128              // queries per block (4 waves x 32)
#define BN 64                // keys per tile
#define NTILES 32
#define L2E 1.44269504f

// ---- workspace layout (bytes) ----
//  [0, 4MB)              Kh  f16 [B][K][H]      stored[k][h ^ ((k&7)<<3)]
//  [4MB, 8MB)            Vth f16 [B][kt][H][64] stored[h][n ^ ((h&7)<<3)]
//  [8MB, +splits*4MB)    O partials f16 (normalized by split denom), [blk128][q][h]
//  then m (f32) splits*16384, then l (f32) splits*16384
#define KH_HALVES      ((size_t)8 * KK * HH)
#define PREP_BYTES     (KH_HALVES * 4)
#define OSPLIT_BYTES   ((size_t)128 * QBM * HH * 2)    // 4 MB per split
#define MLSPLIT_FLOATS ((size_t)128 * QBM)             // 16384 per split

union U32H { unsigned int u; _Float16 h[2]; };
union U64H { unsigned long long u; _Float16 h[4]; };
union H2I  { fp16x2 h; int i; };
union I4H8 { int i[4]; half8 h; };

typedef __attribute__((address_space(1))) const void gvoid;
typedef __attribute__((address_space(3))) void lvoid;

#define WAITVM4 asm volatile("s_waitcnt vmcnt(4)" ::: "memory")
#define WAITVM0 asm volatile("s_waitcnt vmcnt(0)" ::: "memory")
static __device__ __forceinline__ void wgbar() {
    asm volatile("" ::: "memory");
    __builtin_amdgcn_s_barrier();
    asm volatile("" ::: "memory");
}

// ---------------------------------------------------------------------------
// prep: history f32 -> Kh (row-major f16, swizzled) + Vth (transposed f16,
// swizzled). One block per (b, kt) tile.  (verified format, unchanged)
// ---------------------------------------------------------------------------
__launch_bounds__(256)
__global__ void attn_prep_k(const float* __restrict__ history,
                            _Float16* __restrict__ wsh) {
    __shared__ __align__(16) _Float16 Ks[BN * HH];
    __shared__ __align__(16) _Float16 Vt[HH * BN];

    const int tid = threadIdx.x;
    const int bid = blockIdx.x;          // 256 = 8 b * 32 kt
    const int b   = bid >> 5;
    const int kt  = bid & 31;

    const float* hb = history + ((size_t)b * KK + (size_t)kt * BN) * HH;
    const int r0 = tid >> 5;
    const int c4 = (tid & 31) * 4;
    #pragma unroll
    for (int j = 0; j < 8; ++j) {
        const int k = r0 + 8 * j;
        const float4 g = *(const float4*)(hb + (size_t)k * HH + c4);
        half4 hv;
        hv[0] = (_Float16)g.x; hv[1] = (_Float16)g.y;
        hv[2] = (_Float16)g.z; hv[3] = (_Float16)g.w;
        *(half4*)&Ks[k * HH + (c4 ^ ((k & 7) << 3))] = hv;
    }
    __syncthreads();

    {
        const int h0  = 2 * (tid & 63);
        const int n0t = (tid >> 6) * 16;
        half8 ra0, ra1, rb0, rb1;
        #pragma unroll
        for (int i = 0; i < 8; ++i) {
            const int n = n0t + i;
            U32H t; t.u = *(const unsigned int*)&Ks[n * HH + (h0 ^ ((n & 7) << 3))];
            ra0[i] = t.h[0]; rb0[i] = t.h[1];
        }
        #pragma unroll
        for (int i = 8; i < 16; ++i) {
            const int n = n0t + i;
            U32H t; t.u = *(const unsigned int*)&Ks[n * HH + (h0 ^ ((n & 7) << 3))];
            ra1[i - 8] = t.h[0]; rb1[i - 8] = t.h[1];
        }
        const int th0 = (h0 & 7) << 3;
        const int th1 = ((h0 + 1) & 7) << 3;
        *(half8*)&Vt[(h0    ) * BN + ((n0t    ) ^ th0)] = ra0;
        *(half8*)&Vt[(h0    ) * BN + ((n0t + 8) ^ th0)] = ra1;
        *(half8*)&Vt[(h0 + 1) * BN + ((n0t    ) ^ th1)] = rb0;
        *(half8*)&Vt[(h0 + 1) * BN + ((n0t + 8) ^ th1)] = rb1;
    }
    __syncthreads();

    _Float16* kdst = wsh + ((size_t)b * KK + (size_t)kt * BN) * HH;
    _Float16* vdst = wsh + KH_HALVES + ((size_t)(b * NTILES + kt)) * (HH * BN);
    const f32x4* ksrc = (const f32x4*)Ks;
    const f32x4* vsrc = (const f32x4*)Vt;
    #pragma unroll
    for (int i = 0; i < 4; ++i) {
        ((f32x4*)kdst)[i * 256 + tid] = ksrc[i * 256 + tid];
        ((f32x4*)vdst)[i * 256 + tid] = vsrc[i * 256 + tid];
    }
}

// ---------------------------------------------------------------------------
// main: 4 waves x 32 queries, K dbuf + V single (48KB LDS, 3 blocks/CU),
// 3 barriers/kt, counted vmcnt.
// ---------------------------------------------------------------------------
__launch_bounds__(256, 3)
__global__ void attn_main_k(const float* __restrict__ out_state,
                            const _Float16* __restrict__ wsh,
                            float* __restrict__ out,
                            char* __restrict__ wsb,
                            int splits) {
    __shared__ __align__(16) _Float16 KsL[2][BN * HH];   // 2 x 16KB, rows swizzled
    __shared__ __align__(16) _Float16 VtL[HH * BN];      // 16KB, rows swizzled

    const int tid  = threadIdx.x;
    const int wave = tid >> 6;           // 0..3
    const int lane = tid & 63;
    const int l31  = lane & 31;
    const int hi   = lane >> 5;
    const int swzk = (lane & 7) << 3;    // (row&7)<<3 with row ≡ lane (mod 8|32)

    // XCD-grouped work mapping (bijective; grid = 128*splits, multiple of 8)
    const int nwg  = gridDim.x;
    const int cpx  = nwg >> 3;
    const int work = (blockIdx.x & 7) * cpx + (blockIdx.x >> 3);
    const int s    = work >> 7;          // split id (128 works per split)
    const int r128 = work & 127;
    const int b    = r128 >> 4;
    const int qb   = r128 & 15;
    const int q    = qb * QBM + wave * 32 + l31;   // this lane's query row

    const int kt0 = (NTILES * s) / splits;
    const int kt1 = (NTILES * (s + 1)) / splits;

    const _Float16* khb = wsh + (size_t)b * KK * HH;
    const _Float16* vtb = wsh + KH_HALVES + (size_t)b * NTILES * (HH * BN);

    // DMA: 16KB tile = 16 chunks of 1KB; wave w takes chunks {4c + w}, c<4.
    auto issueK = [&](int t, int pb) {
        const char* g = (const char*)(khb + (size_t)t * (BN * HH));
        #pragma unroll
        for (int c = 0; c < 4; ++c) {
            const int off = (c * 4 + wave) * 1024 + lane * 16;
            __builtin_amdgcn_global_load_lds((gvoid*)(g + off),
                                             (lvoid*)((char*)KsL[pb] + off), 16, 0, 0);
        }
    };
    auto issueV = [&](int t) {
        const char* g = (const char*)(vtb + (size_t)t * (HH * BN));
        #pragma unroll
        for (int c = 0; c < 4; ++c) {
            const int off = (c * 4 + wave) * 1024 + lane * 16;
            __builtin_amdgcn_global_load_lds((gvoid*)(g + off),
                                             (lvoid*)((char*)VtL + off), 16, 0, 0);
        }
    };

    // Q loads first (their completion-wait then doesn't drain the DMA queue)
    float4 qa[16];
    {
        const float* qrow = out_state + ((size_t)b * QQ + q) * HH;
        #pragma unroll
        for (int hs = 0; hs < 8; ++hs) {
            qa[2 * hs]     = *(const float4*)(qrow + hs * 16 + hi * 8);
            qa[2 * hs + 1] = *(const float4*)(qrow + hs * 16 + hi * 8 + 4);
        }
    }
    issueK(kt0, 0);
    issueV(kt0);

    // fast tanh (f16-accurate): 1 - 2/(exp2(2*log2(e)*x)+1)
    auto th = [](float x) {
        const float e = __builtin_amdgcn_exp2f(x * (2.0f * L2E));
        return 1.0f - 2.0f * __builtin_amdgcn_rcpf(e + 1.0f);
    };
    half8 qf[8];   // B-frag: lane holds Q[q][hs*16 + hi*8 + j]
    #pragma unroll
    for (int hs = 0; hs < 8; ++hs) {
        const float4 a = qa[2 * hs], c = qa[2 * hs + 1];
        qf[hs][0] = (_Float16)th(a.x); qf[hs][1] = (_Float16)th(a.y);
        qf[hs][2] = (_Float16)th(a.z); qf[hs][3] = (_Float16)th(a.w);
        qf[hs][4] = (_Float16)th(c.x); qf[hs][5] = (_Float16)th(c.y);
        qf[hs][6] = (_Float16)th(c.z); qf[hs][7] = (_Float16)th(c.w);
    }

    f32x16 O[4];                 // O^T: h = ht*32 + (r&3)+8*(r>>2)+4*hi, col q
    #pragma unroll
    for (int i = 0; i < 4; ++i)
        #pragma unroll
        for (int r = 0; r < 16; ++r) O[i][r] = 0.f;
    float Osum = 0.f;
    float rmax = -3.0e38f;

    const H2I one2 = { fp16x2{(__fp16)1.f, (__fp16)1.f} };

    for (int kt = kt0; kt < kt1; ++kt) {
        const int  pb   = (kt - kt0) & 1;
        const bool more = (kt + 1 < kt1);

        // FIFO per wave at entry: [K(kt) x4, V(kt) x4] -> wait K(kt)
        WAITVM4;
        wgbar();                 // bar_A: K(kt) visible to all
        if (more) issueK(kt + 1, pb ^ 1);   // other K buffer; flies a full iteration

        // ---- S^T = K . Q^T  (keys: S0 tile rows 0-31, S1 rows 32-63)
        f32x16 S0, S1;
        #pragma unroll
        for (int r = 0; r < 16; ++r) { S0[r] = 0.f; S1[r] = 0.f; }
        __builtin_amdgcn_s_setprio(1);
        #pragma unroll
        for (int hs = 0; hs < 8; ++hs) {
            const int col = (hs * 16 + hi * 8) ^ swzk;
            const half8 k0 = *(const half8*)&KsL[pb][l31 * 128 + col];
            const half8 k1 = *(const half8*)&KsL[pb][(l31 + 32) * 128 + col];
            S0 = __builtin_amdgcn_mfma_f32_32x32x16_f16(k0, qf[hs], S0, 0, 0, 0);
            S1 = __builtin_amdgcn_mfma_f32_32x32x16_f16(k1, qf[hs], S1, 0, 0, 0);
        }
        __builtin_amdgcn_s_setprio(0);

        // ---- online softmax; row-max via v_max3 tree (fmaxf(fmaxf) fuses)
        float tmax = fmaxf(S0[14], S0[15]);
        #pragma unroll
        for (int r = 0; r < 14; r += 2) tmax = fmaxf(fmaxf(S0[r], S0[r + 1]), tmax);
        #pragma unroll
        for (int r = 0; r < 16; r += 2) tmax = fmaxf(fmaxf(S1[r], S1[r + 1]), tmax);
        tmax = fmaxf(tmax, __shfl_xor(tmax, 32, 64));

        if (!__all(tmax <= rmax)) {
            const float nm    = fmaxf(rmax, tmax);
            const float alpha = __builtin_amdgcn_exp2f((rmax - nm) * L2E);
            rmax = nm;
            #pragma unroll
            for (int i = 0; i < 4; ++i) O[i] *= alpha;
            Osum *= alpha;
        }

        #pragma unroll
        for (int r = 0; r < 16; ++r) S0[r] = __builtin_amdgcn_exp2f((S0[r] - rmax) * L2E);
        #pragma unroll
        for (int r = 0; r < 16; ++r) S1[r] = __builtin_amdgcn_exp2f((S1[r] - rmax) * L2E);

        // ---- pack P to f16 dwords: octet M holds keys 8M + 4*hi + {0..3}
        int d0[8], d1[8];
        #pragma unroll
        for (int M = 0; M < 8; ++M) {
            const int r0 = (M & 3) * 4;
            H2I u0, u1;
            if (M < 4) {
                u0.h = __builtin_amdgcn_cvt_pkrtz(S0[r0], S0[r0 + 1]);
                u1.h = __builtin_amdgcn_cvt_pkrtz(S0[r0 + 2], S0[r0 + 3]);
            } else {
                u0.h = __builtin_amdgcn_cvt_pkrtz(S1[r0], S1[r0 + 1]);
                u1.h = __builtin_amdgcn_cvt_pkrtz(S1[r0 + 2], S1[r0 + 3]);
            }
            d0[M] = u0.i; d1[M] = u1.i;
        }

        // ---- row-sum of the exact f16 P values via fdot2 (f32 accumulate)
        {
            float ls = 0.f;
            #pragma unroll
            for (int M = 0; M < 8; ++M) {
                H2I a; a.i = d0[M];
                ls = __builtin_amdgcn_fdot2(a.h, one2.h, ls, false);
            }
            #pragma unroll
            for (int M = 0; M < 8; ++M) {
                H2I a; a.i = d1[M];
                ls = __builtin_amdgcn_fdot2(a.h, one2.h, ls, false);
            }
            Osum += ls + __shfl_xor(ls, 32, 64);
        }

        // FIFO: [V(kt) x4, (K(kt+1) x4)?] -> wait V(kt)
        if (more) { WAITVM4; } else { WAITVM0; }
        wgbar();                 // bar_B: V(kt) visible; all waves past QK(kt)

        // ---- O^T += V^T . P^T ; B-frag(ns) = keys 16ns + 8hi + {0..7}
        __builtin_amdgcn_s_setprio(1);
        #pragma unroll
        for (int ns = 0; ns < 4; ++ns) {
            const int x  = d0[2 * ns],     x2 = d1[2 * ns];
            const int y  = d0[2 * ns + 1], y2 = d1[2 * ns + 1];
            const int px  = __shfl_xor(x, 32, 64),  px2 = __shfl_xor(x2, 32, 64);
            const int py  = __shfl_xor(y, 32, 64),  py2 = __shfl_xor(y2, 32, 64);
            I4H8 bf;
            bf.i[0] = hi ? py  : x;    // j0,1
            bf.i[1] = hi ? py2 : x2;   // j2,3
            bf.i[2] = hi ? y   : px;   // j4,5
            bf.i[3] = hi ? y2  : px2;  // j6,7
            #pragma unroll
            for (int ht = 0; ht < 4; ++ht) {
                const half8 vf = *(const half8*)
                    &VtL[(ht * 32 + l31) * 64 + ((ns * 16 + hi * 8) ^ swzk)];
                O[ht] = __builtin_amdgcn_mfma_f32_32x32x16_f16(vf, bf.h, O[ht], 0, 0, 0);
            }
        }
        __builtin_amdgcn_s_setprio(0);

        wgbar();                 // bar_C: all waves done reading VtL(kt)
        if (more) issueV(kt + 1);
    }

    // ---- epilogue: lane writes h = ht*32 + 8m + 4hi + {0..3} of query q
    if (splits == 1) {
        const float inv = 1.0f / Osum;
        float* orow = out + ((size_t)b * QQ + q) * HH;
        #pragma unroll
        for (int ht = 0; ht < 4; ++ht)
            #pragma unroll
            for (int m = 0; m < 4; ++m) {
                f32x4 v;
                v[0] = O[ht][4 * m]     * inv; v[1] = O[ht][4 * m + 1] * inv;
                v[2] = O[ht][4 * m + 2] * inv; v[3] = O[ht][4 * m + 3] * inv;
                *(f32x4*)&orow[ht * 32 + 8 * m + 4 * hi] = v;
            }
    } else {
        const float inv = 1.0f / Osum;
        _Float16* oh = (_Float16*)(wsb + PREP_BYTES)
                     + ((size_t)(s * 128 + r128) * QBM + wave * 32 + l31) * HH;
        #pragma unroll
        for (int ht = 0; ht < 4; ++ht)
            #pragma unroll
            for (int m = 0; m < 4; ++m) {
                half4 hv;
                hv[0] = (_Float16)(O[ht][4 * m]     * inv);
                hv[1] = (_Float16)(O[ht][4 * m + 1] * inv);
                hv[2] = (_Float16)(O[ht][4 * m + 2] * inv);
                hv[3] = (_Float16)(O[ht][4 * m + 3] * inv);
                *(half4*)&oh[ht * 32 + 8 * m + 4 * hi] = hv;
            }
        if (!hi) {
            float* wm = (float*)(wsb + PREP_BYTES + (size_t)splits * OSPLIT_BYTES);
            const size_t idx = (size_t)(s * 128 + r128) * QBM + wave * 32 + l31;
            wm[idx] = rmax;
            wm[(size_t)splits * MLSPLIT_FLOATS + idx] = Osum;
        }
    }
}

// ---------------------------------------------------------------------------
// combine: 4 h per thread (8B partial loads, f32x4 store); templated splits
// ---------------------------------------------------------------------------
template<int SPL>
__launch_bounds__(256)
__global__ void attn_combine_k(const char* __restrict__ wsb,
                               float* __restrict__ out) {
    const int idx = blockIdx.x * 256 + threadIdx.x;   // over B*QQ*HH/4 = 2^19
    const int h4  = idx & 31;
    const int q   = (idx >> 5) & 2047;
    const int b   = idx >> 16;
    const int blk = b * 16 + (q >> 7);                // 128-query blocks
    const int qr  = q & 127;

    const _Float16* oh = (const _Float16*)(wsb + PREP_BYTES);
    const float* wm = (const float*)(wsb + PREP_BYTES + (size_t)SPL * OSPLIT_BYTES);
    const float* wl = wm + (size_t)SPL * MLSPLIT_FLOATS;

    float ms[SPL];
    float M = -3.0e38f;
    #pragma unroll
    for (int s = 0; s < SPL; ++s) {
        ms[s] = wm[(size_t)(s * 128 + blk) * QBM + qr];
        M = fmaxf(M, ms[s]);
    }
    float denom = 0.f;
    float v0 = 0.f, v1 = 0.f, v2 = 0.f, v3 = 0.f;
    #pragma unroll
    for (int s = 0; s < SPL; ++s) {
        const float wgt = exp2f((ms[s] - M) * L2E) * wl[(size_t)(s * 128 + blk) * QBM + qr];
        denom += wgt;
        U64H t;
        t.u = *(const unsigned long long*)&oh[((size_t)(s * 128 + blk) * QBM + qr) * HH
                                              + 4 * h4];
        v0 += wgt * (float)t.h[0];
        v1 += wgt * (float)t.h[1];
        v2 += wgt * (float)t.h[2];
        v3 += wgt * (float)t.h[3];
    }
    const float inv = 1.0f / denom;
    f32x4 r; r[0] = v0 * inv; r[1] = v1 * inv; r[2] = v2 * inv; r[3] = v3 * inv;
    *(f32x4*)&out[((size_t)(b * QQ + q)) * HH + 4 * h4] = r;
}

extern "C" void kernel_launch(void* const* d_in, const int* in_sizes, int n_in,
                              void* d_out, int out_size, void* d_ws, size_t ws_size,
                              hipStream_t stream) {
    const float* out_state = (const float*)d_in[0];
    const float* history   = (const float*)d_in[1];
    float* out = (float*)d_out;
    char* wsb  = (char*)d_ws;

    const size_t need6 = PREP_BYTES + 6 * OSPLIT_BYTES + 6 * 2 * MLSPLIT_FLOATS * 4;
    const size_t need4 = PREP_BYTES + 4 * OSPLIT_BYTES + 4 * 2 * MLSPLIT_FLOATS * 4;
    const size_t need3 = PREP_BYTES + 3 * OSPLIT_BYTES + 3 * 2 * MLSPLIT_FLOATS * 4;
    const int splits = (ws_size >= need6) ? 6
                     : (ws_size >= need4) ? 4
                     : (ws_size >= need3) ? 3 : 1;

    attn_prep_k<<<dim3(256), dim3(256), 0, stream>>>(history, (_Float16*)wsb);
    attn_main_k<<<dim3(128 * splits), dim3(256), 0, stream>>>(out_state, (const _Float16*)wsb,
                                                              out, wsb, splits);
    if (splits == 6)
        attn_combine_k<6><<<dim3(2048), dim3(256), 0, stream>>>(wsb, out);
    else if (splits == 4)
        attn_combine_k<4><<<dim3(2048), dim3(256), 0, stream>>>(wsb, out);
    else if (splits == 3)
        attn_combine_k<3><<<dim3(2048), dim3(256), 0, stream>>>(wsb, out);
}

// Round 9
// 107.349 us; speedup vs baseline: 1.2552x; 1.2552x over previous
//
#include <hip/hip_runtime.h>
#include <math.h>

// Attn: out = softmax(tanh(Q) @ H^T) @ H ; B=8, Q=2048, K=2048, Hdim=128, fp32 in/out.
// R11 = R8 structure (best measured: 107.97us) + softmax VALU micro-cuts from R9.
//   main: 4 waves x 32 q (128 q/block), K AND V double-buffered (64KB LDS, 2 blocks/CU),
//         2 barriers/kt, counted vmcnt (WAITVM4 steady state), splits=4 (grid 512).
//         Swapped QK^T (32x32x16 MFMA), in-register softmax + P assembly.
//   micro-cuts: row-max via max3 tree; row-sum via fdot2 on packed f16 P.
//   R9/R10 lesson: 3rd barrier + V-single-buffer + splits=6 SERIALIZED (65us main) —
//   barrier-to-barrier critical path is the binding resource, not waves/CU.

typedef _Float16 half8  __attribute__((ext_vector_type(8)));
typedef _Float16 half4  __attribute__((ext_vector_type(4)));
typedef __fp16   fp16x2 __attribute__((ext_vector_type(2)));   // cvt_pkrtz/fdot2 native type
typedef float    f32x4  __attribute__((ext_vector_type(4)));
typedef float    f32x16 __attribute__((ext_vector_type(16)));

#define QQ 2048
#define KK 2048
#define HH 128
#define QBM 128              // queries per block (4 waves x 32)
#define BN 64                // keys per tile
#define NTILES 32
#define L2E 1.44269504f

// ---- workspace layout (bytes) ----
//  [0, 4MB)              Kh  f16 [B][K][H]      stored[k][h ^ ((k&7)<<3)]
//  [4MB, 8MB)            Vth f16 [B][kt][H][64] stored[h][n ^ ((h&7)<<3)]
//  [8MB, +splits*4MB)    O partials f16 (normalized by split denom), [blk128][q][h]
//  then m (f32) splits*16384, then l (f32) splits*16384
#define KH_HALVES      ((size_t)8 * KK * HH)
#define PREP_BYTES     (KH_HALVES * 4)
#define OSPLIT_BYTES   ((size_t)128 * QBM * HH * 2)    // 4 MB per split
#define MLSPLIT_FLOATS ((size_t)128 * QBM)             // 16384 per split

union U32H { unsigned int u; _Float16 h[2]; };
union U64H { unsigned long long u; _Float16 h[4]; };
union H2I  { fp16x2 h; int i; };
union I4H8 { int i[4]; half8 h; };

typedef __attribute__((address_space(1))) const void gvoid;
typedef __attribute__((address_space(3))) void lvoid;

#define WAITVM4 asm volatile("s_waitcnt vmcnt(4)" ::: "memory")
#define WAITVM0 asm volatile("s_waitcnt vmcnt(0)" ::: "memory")
static __device__ __forceinline__ void wgbar() {
    asm volatile("" ::: "memory");
    __builtin_amdgcn_s_barrier();
    asm volatile("" ::: "memory");
}

// ---------------------------------------------------------------------------
// prep: history f32 -> Kh (row-major f16, swizzled) + Vth (transposed f16,
// swizzled). One block per (b, kt) tile.  (verified format, unchanged)
// ---------------------------------------------------------------------------
__launch_bounds__(256)
__global__ void attn_prep_k(const float* __restrict__ history,
                            _Float16* __restrict__ wsh) {
    __shared__ __align__(16) _Float16 Ks[BN * HH];
    __shared__ __align__(16) _Float16 Vt[HH * BN];

    const int tid = threadIdx.x;
    const int bid = blockIdx.x;          // 256 = 8 b * 32 kt
    const int b   = bid >> 5;
    const int kt  = bid & 31;

    const float* hb = history + ((size_t)b * KK + (size_t)kt * BN) * HH;
    const int r0 = tid >> 5;
    const int c4 = (tid & 31) * 4;
    #pragma unroll
    for (int j = 0; j < 8; ++j) {
        const int k = r0 + 8 * j;
        const float4 g = *(const float4*)(hb + (size_t)k * HH + c4);
        half4 hv;
        hv[0] = (_Float16)g.x; hv[1] = (_Float16)g.y;
        hv[2] = (_Float16)g.z; hv[3] = (_Float16)g.w;
        *(half4*)&Ks[k * HH + (c4 ^ ((k & 7) << 3))] = hv;
    }
    __syncthreads();

    {
        const int h0  = 2 * (tid & 63);
        const int n0t = (tid >> 6) * 16;
        half8 ra0, ra1, rb0, rb1;
        #pragma unroll
        for (int i = 0; i < 8; ++i) {
            const int n = n0t + i;
            U32H t; t.u = *(const unsigned int*)&Ks[n * HH + (h0 ^ ((n & 7) << 3))];
            ra0[i] = t.h[0]; rb0[i] = t.h[1];
        }
        #pragma unroll
        for (int i = 8; i < 16; ++i) {
            const int n = n0t + i;
            U32H t; t.u = *(const unsigned int*)&Ks[n * HH + (h0 ^ ((n & 7) << 3))];
            ra1[i - 8] = t.h[0]; rb1[i - 8] = t.h[1];
        }
        const int th0 = (h0 & 7) << 3;
        const int th1 = ((h0 + 1) & 7) << 3;
        *(half8*)&Vt[(h0    ) * BN + ((n0t    ) ^ th0)] = ra0;
        *(half8*)&Vt[(h0    ) * BN + ((n0t + 8) ^ th0)] = ra1;
        *(half8*)&Vt[(h0 + 1) * BN + ((n0t    ) ^ th1)] = rb0;
        *(half8*)&Vt[(h0 + 1) * BN + ((n0t + 8) ^ th1)] = rb1;
    }
    __syncthreads();

    _Float16* kdst = wsh + ((size_t)b * KK + (size_t)kt * BN) * HH;
    _Float16* vdst = wsh + KH_HALVES + ((size_t)(b * NTILES + kt)) * (HH * BN);
    const f32x4* ksrc = (const f32x4*)Ks;
    const f32x4* vsrc = (const f32x4*)Vt;
    #pragma unroll
    for (int i = 0; i < 4; ++i) {
        ((f32x4*)kdst)[i * 256 + tid] = ksrc[i * 256 + tid];
        ((f32x4*)vdst)[i * 256 + tid] = vsrc[i * 256 + tid];
    }
}

// ---------------------------------------------------------------------------
// main: 4 waves x 32 queries (128 q/block), double-buffered K/V, 2 barriers/kt.
// ---------------------------------------------------------------------------
__launch_bounds__(256, 2)
__global__ void attn_main_k(const float* __restrict__ out_state,
                            const _Float16* __restrict__ wsh,
                            float* __restrict__ out,
                            char* __restrict__ wsb,
                            int splits) {
    __shared__ __align__(16) _Float16 KsL[2][BN * HH];   // 2 x 16KB, rows swizzled
    __shared__ __align__(16) _Float16 VtL[2][HH * BN];   // 2 x 16KB, rows swizzled

    const int tid  = threadIdx.x;
    const int wave = tid >> 6;           // 0..3
    const int lane = tid & 63;
    const int l31  = lane & 31;
    const int hi   = lane >> 5;
    const int swzk = (lane & 7) << 3;    // (row&7)<<3 with row ≡ lane (mod 8|32)

    // XCD-grouped work mapping (bijective; grid = 128*splits, multiple of 8)
    const int nwg  = gridDim.x;
    const int cpx  = nwg >> 3;
    const int work = (blockIdx.x & 7) * cpx + (blockIdx.x >> 3);
    const int s    = work >> 7;          // split id (128 works per split)
    const int r128 = work & 127;
    const int b    = r128 >> 4;
    const int qb   = r128 & 15;
    const int q    = qb * QBM + wave * 32 + l31;   // this lane's query row

    const int kt0 = (NTILES * s) / splits;
    const int kt1 = (NTILES * (s + 1)) / splits;

    const _Float16* khb = wsh + (size_t)b * KK * HH;
    const _Float16* vtb = wsh + KH_HALVES + (size_t)b * NTILES * (HH * BN);

    // DMA: 16KB tile = 16 chunks of 1KB; wave w takes chunks {4c + w}, c<4.
    auto issueK = [&](int t, int pb) {
        const char* g = (const char*)(khb + (size_t)t * (BN * HH));
        #pragma unroll
        for (int c = 0; c < 4; ++c) {
            const int off = (c * 4 + wave) * 1024 + lane * 16;
            __builtin_amdgcn_global_load_lds((gvoid*)(g + off),
                                             (lvoid*)((char*)KsL[pb] + off), 16, 0, 0);
        }
    };
    auto issueV = [&](int t, int pb) {
        const char* g = (const char*)(vtb + (size_t)t * (HH * BN));
        #pragma unroll
        for (int c = 0; c < 4; ++c) {
            const int off = (c * 4 + wave) * 1024 + lane * 16;
            __builtin_amdgcn_global_load_lds((gvoid*)(g + off),
                                             (lvoid*)((char*)VtL[pb] + off), 16, 0, 0);
        }
    };

    // Q loads first (their completion-wait then doesn't drain the DMA queue)
    float4 qa[16];
    {
        const float* qrow = out_state + ((size_t)b * QQ + q) * HH;
        #pragma unroll
        for (int hs = 0; hs < 8; ++hs) {
            qa[2 * hs]     = *(const float4*)(qrow + hs * 16 + hi * 8);
            qa[2 * hs + 1] = *(const float4*)(qrow + hs * 16 + hi * 8 + 4);
        }
    }
    issueK(kt0, 0);
    issueV(kt0, 0);

    // fast tanh (f16-accurate): 1 - 2/(exp2(2*log2(e)*x)+1)
    auto th = [](float x) {
        const float e = __builtin_amdgcn_exp2f(x * (2.0f * L2E));
        return 1.0f - 2.0f * __builtin_amdgcn_rcpf(e + 1.0f);
    };
    half8 qf[8];   // B-frag: lane holds Q[q][hs*16 + hi*8 + j]
    #pragma unroll
    for (int hs = 0; hs < 8; ++hs) {
        const float4 a = qa[2 * hs], c = qa[2 * hs + 1];
        qf[hs][0] = (_Float16)th(a.x); qf[hs][1] = (_Float16)th(a.y);
        qf[hs][2] = (_Float16)th(a.z); qf[hs][3] = (_Float16)th(a.w);
        qf[hs][4] = (_Float16)th(c.x); qf[hs][5] = (_Float16)th(c.y);
        qf[hs][6] = (_Float16)th(c.z); qf[hs][7] = (_Float16)th(c.w);
    }

    f32x16 O[4];                 // O^T: h = ht*32 + (r&3)+8*(r>>2)+4*hi, col q
    #pragma unroll
    for (int i = 0; i < 4; ++i)
        #pragma unroll
        for (int r = 0; r < 16; ++r) O[i][r] = 0.f;
    float Osum = 0.f;
    float rmax = -3.0e38f;

    const H2I one2 = { fp16x2{(__fp16)1.f, (__fp16)1.f} };

    for (int kt = kt0; kt < kt1; ++kt) {
        const int  pb   = (kt - kt0) & 1;
        const bool more = (kt + 1 < kt1);

        // FIFO per wave at entry: [K(kt) x4, V(kt) x4] -> wait K(kt)
        WAITVM4;
        wgbar();                 // bar1: K(kt) visible; iter kt-1 fully done
        if (more) issueK(kt + 1, pb ^ 1);   // flies under QK + softmax + PV

        // ---- S^T = K . Q^T  (keys: S0 tile rows 0-31, S1 rows 32-63)
        f32x16 S0, S1;
        #pragma unroll
        for (int r = 0; r < 16; ++r) { S0[r] = 0.f; S1[r] = 0.f; }
        __builtin_amdgcn_s_setprio(1);
        #pragma unroll
        for (int hs = 0; hs < 8; ++hs) {
            const int col = (hs * 16 + hi * 8) ^ swzk;
            const half8 k0 = *(const half8*)&KsL[pb][l31 * 128 + col];
            const half8 k1 = *(const half8*)&KsL[pb][(l31 + 32) * 128 + col];
            S0 = __builtin_amdgcn_mfma_f32_32x32x16_f16(k0, qf[hs], S0, 0, 0, 0);
            S1 = __builtin_amdgcn_mfma_f32_32x32x16_f16(k1, qf[hs], S1, 0, 0, 0);
        }
        __builtin_amdgcn_s_setprio(0);

        // ---- online softmax; row-max via max3 tree (fmaxf(fmaxf,..) fuses to v_max3)
        float tmax = fmaxf(S0[14], S0[15]);
        #pragma unroll
        for (int r = 0; r < 14; r += 2) tmax = fmaxf(fmaxf(S0[r], S0[r + 1]), tmax);
        #pragma unroll
        for (int r = 0; r < 16; r += 2) tmax = fmaxf(fmaxf(S1[r], S1[r + 1]), tmax);
        tmax = fmaxf(tmax, __shfl_xor(tmax, 32, 64));

        if (!__all(tmax <= rmax)) {
            const float nm    = fmaxf(rmax, tmax);
            const float alpha = __builtin_amdgcn_exp2f((rmax - nm) * L2E);
            rmax = nm;
            #pragma unroll
            for (int i = 0; i < 4; ++i) O[i] *= alpha;
            Osum *= alpha;
        }

        #pragma unroll
        for (int r = 0; r < 16; ++r) S0[r] = __builtin_amdgcn_exp2f((S0[r] - rmax) * L2E);
        #pragma unroll
        for (int r = 0; r < 16; ++r) S1[r] = __builtin_amdgcn_exp2f((S1[r] - rmax) * L2E);

        // ---- pack P to f16 dwords: octet M holds keys 8M + 4*hi + {0..3}
        int d0[8], d1[8];
        #pragma unroll
        for (int M = 0; M < 8; ++M) {
            const int r0 = (M & 3) * 4;
            H2I u0, u1;
            if (M < 4) {
                u0.h = __builtin_amdgcn_cvt_pkrtz(S0[r0], S0[r0 + 1]);
                u1.h = __builtin_amdgcn_cvt_pkrtz(S0[r0 + 2], S0[r0 + 3]);
            } else {
                u0.h = __builtin_amdgcn_cvt_pkrtz(S1[r0], S1[r0 + 1]);
                u1.h = __builtin_amdgcn_cvt_pkrtz(S1[r0 + 2], S1[r0 + 3]);
            }
            d0[M] = u0.i; d1[M] = u1.i;
        }

        // ---- row-sum of the exact f16 P values via fdot2 (f32 accumulate)
        {
            float ls = 0.f;
            #pragma unroll
            for (int M = 0; M < 8; ++M) {
                H2I a; a.i = d0[M];
                ls = __builtin_amdgcn_fdot2(a.h, one2.h, ls, false);
            }
            #pragma unroll
            for (int M = 0; M < 8; ++M) {
                H2I a; a.i = d1[M];
                ls = __builtin_amdgcn_fdot2(a.h, one2.h, ls, false);
            }
            Osum += ls + __shfl_xor(ls, 32, 64);
        }

        // FIFO: [V(kt) x4, (K(kt+1) x4)?] -> wait V(kt)
        if (more) { WAITVM4; } else { WAITVM0; }
        wgbar();                 // bar2: V(kt) visible; all waves past QK(kt)
        if (more) issueV(kt + 1, pb ^ 1);   // flies under PV + next QK

        // ---- O^T += V^T . P^T ; B-frag(ns) = keys 16ns + 8hi + {0..7}
        __builtin_amdgcn_s_setprio(1);
        #pragma unroll
        for (int ns = 0; ns < 4; ++ns) {
            const int x  = d0[2 * ns],     x2 = d1[2 * ns];
            const int y  = d0[2 * ns + 1], y2 = d1[2 * ns + 1];
            const int px  = __shfl_xor(x, 32, 64),  px2 = __shfl_xor(x2, 32, 64);
            const int py  = __shfl_xor(y, 32, 64),  py2 = __shfl_xor(y2, 32, 64);
            I4H8 bf;
            bf.i[0] = hi ? py  : x;    // j0,1
            bf.i[1] = hi ? py2 : x2;   // j2,3
            bf.i[2] = hi ? y   : px;   // j4,5
            bf.i[3] = hi ? y2  : px2;  // j6,7
            #pragma unroll
            for (int ht = 0; ht < 4; ++ht) {
                const half8 vf = *(const half8*)
                    &VtL[pb][(ht * 32 + l31) * 64 + ((ns * 16 + hi * 8) ^ swzk)];
                O[ht] = __builtin_amdgcn_mfma_f32_32x32x16_f16(vf, bf.h, O[ht], 0, 0, 0);
            }
        }
        __builtin_amdgcn_s_setprio(0);
    }

    // ---- epilogue: lane writes h = ht*32 + 8m + 4hi + {0..3} of query q
    if (splits == 1) {
        const float inv = 1.0f / Osum;
        float* orow = out + ((size_t)b * QQ + q) * HH;
        #pragma unroll
        for (int ht = 0; ht < 4; ++ht)
            #pragma unroll
            for (int m = 0; m < 4; ++m) {
                f32x4 v;
                v[0] = O[ht][4 * m]     * inv; v[1] = O[ht][4 * m + 1] * inv;
                v[2] = O[ht][4 * m + 2] * inv; v[3] = O[ht][4 * m + 3] * inv;
                *(f32x4*)&orow[ht * 32 + 8 * m + 4 * hi] = v;
            }
    } else {
        const float inv = 1.0f / Osum;
        _Float16* oh = (_Float16*)(wsb + PREP_BYTES)
                     + ((size_t)(s * 128 + r128) * QBM + wave * 32 + l31) * HH;
        #pragma unroll
        for (int ht = 0; ht < 4; ++ht)
            #pragma unroll
            for (int m = 0; m < 4; ++m) {
                half4 hv;
                hv[0] = (_Float16)(O[ht][4 * m]     * inv);
                hv[1] = (_Float16)(O[ht][4 * m + 1] * inv);
                hv[2] = (_Float16)(O[ht][4 * m + 2] * inv);
                hv[3] = (_Float16)(O[ht][4 * m + 3] * inv);
                *(half4*)&oh[ht * 32 + 8 * m + 4 * hi] = hv;
            }
        if (!hi) {
            float* wm = (float*)(wsb + PREP_BYTES + (size_t)splits * OSPLIT_BYTES);
            const size_t idx = (size_t)(s * 128 + r128) * QBM + wave * 32 + l31;
            wm[idx] = rmax;
            wm[(size_t)splits * MLSPLIT_FLOATS + idx] = Osum;
        }
    }
}

// ---------------------------------------------------------------------------
// combine: 4 h per thread (8B partial loads, f32x4 store); templated splits
// ---------------------------------------------------------------------------
template<int SPL>
__launch_bounds__(256)
__global__ void attn_combine_k(const char* __restrict__ wsb,
                               float* __restrict__ out) {
    const int idx = blockIdx.x * 256 + threadIdx.x;   // over B*QQ*HH/4 = 2^19
    const int h4  = idx & 31;
    const int q   = (idx >> 5) & 2047;
    const int b   = idx >> 16;
    const int blk = b * 16 + (q >> 7);                // 128-query blocks
    const int qr  = q & 127;

    const _Float16* oh = (const _Float16*)(wsb + PREP_BYTES);
    const float* wm = (const float*)(wsb + PREP_BYTES + (size_t)SPL * OSPLIT_BYTES);
    const float* wl = wm + (size_t)SPL * MLSPLIT_FLOATS;

    float ms[SPL];
    float M = -3.0e38f;
    #pragma unroll
    for (int s = 0; s < SPL; ++s) {
        ms[s] = wm[(size_t)(s * 128 + blk) * QBM + qr];
        M = fmaxf(M, ms[s]);
    }
    float denom = 0.f;
    float v0 = 0.f, v1 = 0.f, v2 = 0.f, v3 = 0.f;
    #pragma unroll
    for (int s = 0; s < SPL; ++s) {
        const float wgt = exp2f((ms[s] - M) * L2E) * wl[(size_t)(s * 128 + blk) * QBM + qr];
        denom += wgt;
        U64H t;
        t.u = *(const unsigned long long*)&oh[((size_t)(s * 128 + blk) * QBM + qr) * HH
                                              + 4 * h4];
        v0 += wgt * (float)t.h[0];
        v1 += wgt * (float)t.h[1];
        v2 += wgt * (float)t.h[2];
        v3 += wgt * (float)t.h[3];
    }
    const float inv = 1.0f / denom;
    f32x4 r; r[0] = v0 * inv; r[1] = v1 * inv; r[2] = v2 * inv; r[3] = v3 * inv;
    *(f32x4*)&out[((size_t)(b * QQ + q)) * HH + 4 * h4] = r;
}

extern "C" void kernel_launch(void* const* d_in, const int* in_sizes, int n_in,
                              void* d_out, int out_size, void* d_ws, size_t ws_size,
                              hipStream_t stream) {
    const float* out_state = (const float*)d_in[0];
    const float* history   = (const float*)d_in[1];
    float* out = (float*)d_out;
    char* wsb  = (char*)d_ws;

    const size_t need4 = PREP_BYTES + 4 * OSPLIT_BYTES + 4 * 2 * MLSPLIT_FLOATS * 4;
    const size_t need3 = PREP_BYTES + 3 * OSPLIT_BYTES + 3 * 2 * MLSPLIT_FLOATS * 4;
    const int splits = (ws_size >= need4) ? 4 : (ws_size >= need3) ? 3 : 1;

    attn_prep_k<<<dim3(256), dim3(256), 0, stream>>>(history, (_Float16*)wsb);
    attn_main_k<<<dim3(128 * splits), dim3(256), 0, stream>>>(out_state, (const _Float16*)wsb,
                                                              out, wsb, splits);
    if (splits == 4)
        attn_combine_k<4><<<dim3(2048), dim3(256), 0, stream>>>(wsb, out);
    else if (splits == 3)
        attn_combine_k<3><<<dim3(2048), dim3(256), 0, stream>>>(wsb, out);
}